// Round 4
// baseline (2355.717 us; speedup 1.0000x reference)
//
#include <hip/hip_runtime.h>
#include <hip/hip_bf16.h>

#define BB 64
#define SS 128
#define LSRC 256
#define HH 512
#define NHEAD 8
#define HDIM 64
#define VV 8000
#define M1 (BB*SS)     // 8192
#define M2 (BB*LSRC)   // 16384

typedef unsigned short u16;
typedef __attribute__((ext_vector_type(8))) short bf16x8;
typedef __attribute__((ext_vector_type(4))) float f32x4;

__device__ __forceinline__ float b2f(u16 u){
    unsigned int x = ((unsigned int)u) << 16;
    return __uint_as_float(x);
}
__device__ __forceinline__ u16 f2b(float f){
    unsigned int x = __float_as_uint(f);
    x = x + 0x7fffu + ((x >> 16) & 1u);
    return (u16)(x >> 16);
}

// ---------------- dtype probe: bf16 data never has exp>=0x80 (|x|>=2); f32 low-mantissa halves do ~50%
// Also zeroes the GRU barrier counter (runs first on the stream).
__global__ __launch_bounds__(256) void k_probe(const u16* __restrict__ emb, int* __restrict__ flag,
                                               int* __restrict__ bar){
    __shared__ int tot;
    if (threadIdx.x == 0) tot = 0;
    if (threadIdx.x < 16) bar[threadIdx.x] = 0;
    __syncthreads();
    int cnt = 0;
    #pragma unroll
    for (int i = 0; i < 32; i++){
        u16 u = emb[threadIdx.x * 32 + i];
        cnt += (((u >> 7) & 0xFF) >= 0x80);
    }
    #pragma unroll
    for (int off = 1; off < 64; off <<= 1) cnt += __shfl_xor(cnt, off);
    if ((threadIdx.x & 63) == 0) atomicAdd(&tot, cnt);
    __syncthreads();
    if (threadIdx.x == 0) *flag = (tot > 100) ? 1 : 0;
}

// ---------------- input normalization: f32->bf16 convert, or bf16 passthrough copy ----------------
__global__ __launch_bounds__(256) void k_convert(const void* __restrict__ src, u16* __restrict__ dst,
                                                 const int* __restrict__ flag, long n8){
    long i = (long)blockIdx.x * 256 + threadIdx.x;
    if (i >= n8) return;
    if (*flag){
        const float4* s = (const float4*)src;
        float4 a = s[i*2], b = s[i*2+1];
        u16 o[8] = { f2b(a.x), f2b(a.y), f2b(a.z), f2b(a.w), f2b(b.x), f2b(b.y), f2b(b.z), f2b(b.w) };
        *(uint4*)(dst + i*8) = *(const uint4*)o;
    } else {
        *(uint4*)(dst + i*8) = ((const uint4*)src)[i];
    }
}

// ---------------- embed + query_input ----------------
__global__ __launch_bounds__(256) void k_embed(const int* __restrict__ pc,
    const u16* __restrict__ emb, const u16* __restrict__ h0,
    u16* __restrict__ gruin, u16* __restrict__ qin)
{
    int c = blockIdx.x * 256 + threadIdx.x;   // 524288 chunks of 8 elems
    int row = c >> 6;
    int kc = (c & 63) << 3;
    int b = row >> 7;
    int tok = pc[row];
    uint4 e = *(const uint4*)(emb + (long)tok * HH + kc);
    *(uint4*)(gruin + (long)row * (2*HH) + kc) = e;   // char_emb -> gru_input[:, :512]
    uint4 hv = *(const uint4*)(h0 + b * HH + kc);
    const u16* ep = (const u16*)&e;
    const u16* hp = (const u16*)&hv;
    u16 q[8];
    #pragma unroll
    for (int j = 0; j < 8; j++) q[j] = f2b(b2f(ep[j]) + b2f(hp[j]));
    *(uint4*)(qin + (long)row * HH + kc) = *(const uint4*)q;
}

// ---------------- generic bf16 MFMA GEMM: C[M,N] = A[M,K] * W[N,K]^T + bias ----------------
__global__ __launch_bounds__(256) void gemm_bt(
    const u16* __restrict__ A, int lda,
    const u16* __restrict__ W, int ldw,
    const u16* __restrict__ bias,
    u16* __restrict__ Cb, float* __restrict__ Cf, int ldc,
    int N, int K)
{
    __shared__ u16 As[128*64];
    __shared__ u16 Bs[128*64];
    const int tid = threadIdx.x;
    const int wave = tid >> 6, lane = tid & 63;
    const int m0 = blockIdx.x * 128, n0 = blockIdx.y * 128;
    const int wm = (wave & 1) * 64, wn = (wave >> 1) * 64;
    const int lm = lane & 15, lq = lane >> 4;
    f32x4 acc[4][4];
    #pragma unroll
    for (int i = 0; i < 4; i++)
        #pragma unroll
        for (int j = 0; j < 4; j++) acc[i][j] = (f32x4){0.f,0.f,0.f,0.f};

    for (int k0 = 0; k0 < K; k0 += 64) {
        #pragma unroll
        for (int i = 0; i < 4; i++) {
            int chunk = i*256 + tid;               // 1024 chunks of 8 bf16
            int row = chunk >> 3, kc = (chunk & 7) << 3;
            *(uint4*)(As + chunk*8) = *(const uint4*)(A + (long)(m0+row)*lda + k0 + kc);
            int brow = n0 + row; if (brow >= N) brow = N - 1;   // clamp for N=8000 tail
            *(uint4*)(Bs + chunk*8) = *(const uint4*)(W + (long)brow*ldw + k0 + kc);
        }
        __syncthreads();
        #pragma unroll
        for (int kk = 0; kk < 64; kk += 32) {
            bf16x8 af[4], bfr[4];
            #pragma unroll
            for (int i = 0; i < 4; i++){
                af[i]  = *(const bf16x8*)(As + (wm + i*16 + lm)*64 + kk + lq*8);
                bfr[i] = *(const bf16x8*)(Bs + (wn + i*16 + lm)*64 + kk + lq*8);
            }
            #pragma unroll
            for (int mi = 0; mi < 4; mi++)
                #pragma unroll
                for (int ni = 0; ni < 4; ni++)
                    acc[mi][ni] = __builtin_amdgcn_mfma_f32_16x16x32_bf16(af[mi], bfr[ni], acc[mi][ni], 0, 0, 0);
        }
        __syncthreads();
    }
    // C/D layout: col = lane&15, row = (lane>>4)*4 + reg
    #pragma unroll
    for (int ni = 0; ni < 4; ni++){
        int n = n0 + wn + ni*16 + lm;
        if (n >= N) continue;
        float bv = bias ? b2f(bias[n]) : 0.f;
        #pragma unroll
        for (int mi = 0; mi < 4; mi++){
            #pragma unroll
            for (int r = 0; r < 4; r++){
                int m = m0 + wm + mi*16 + lq*4 + r;
                float v = acc[mi][ni][r] + bv;
                if (Cf) Cf[(long)m*ldc + n] = v;
                else    Cb[(long)m*ldc + n] = f2b(v);
            }
        }
    }
}

// ---------------- fused MFMA attention: one block per (b, head) ----------------
// scores = Q[128x64] @ K[256x64]^T * 0.125 -> row softmax -> ctx = P @ V[256x64]
// LDS overlay: Ps reuses the Ks region (Ks dead after QK^T) -> 99 KiB static LDS total.
__global__ __launch_bounds__(256) void k_attn(const u16* __restrict__ Qb,
    const u16* __restrict__ Kb, const u16* __restrict__ Vb, u16* __restrict__ ctxb)
{
    __shared__ u16 smem[64*264 + 4*32*264];   // Vt [16896] + union(Ks[18432], Ps[33792]) = 101,376 B
    u16* Vt = smem;                // V transposed [ch][l], ld=264
    u16* Ks = smem + 64*264;       // K row-major, ld=72 (alive during QK^T only)
    u16* Ps = smem + 64*264;       // per-wave P [32][l], ld=264 (alive during PV only)
    const int bid = blockIdx.x;
    const int h = bid & 7, b = bid >> 3;
    const int tid = threadIdx.x;
    const int wave = tid >> 6, lane = tid & 63;
    const int lm = lane & 15, lq = lane >> 4;
    const long kvbase = (long)b*LSRC*HH + h*HDIM;

    // ---- stage K (row-major) and V (transposed) into LDS ----
    #pragma unroll
    for (int i = 0; i < 8; i++){
        int c = i*256 + tid;                // 2048 chunks: l = c>>3, ch0 = (c&7)*8
        int l = c >> 3, ch0 = (c & 7) << 3;
        uint4 kv = *(const uint4*)(Kb + kvbase + (long)l*HH + ch0);
        *(uint4*)(Ks + l*72 + ch0) = kv;
        uint4 vv = *(const uint4*)(Vb + kvbase + (long)l*HH + ch0);
        const u16* vp = (const u16*)&vv;
        #pragma unroll
        for (int j = 0; j < 8; j++) Vt[(ch0 + j)*264 + l] = vp[j];
    }

    // ---- Q fragments straight from global (wave's 32 rows) ----
    bf16x8 aq[2][2];
    #pragma unroll
    for (int mt = 0; mt < 2; mt++)
        #pragma unroll
        for (int kk = 0; kk < 2; kk++)
            aq[mt][kk] = *(const bf16x8*)(Qb + (long)(b*SS + wave*32 + mt*16 + lm)*HH
                                              + h*HDIM + kk*32 + lq*8);
    __syncthreads();

    // ---- QK^T: 32x256 score tile in registers ----
    f32x4 accs[2][16];
    #pragma unroll
    for (int mt = 0; mt < 2; mt++)
        #pragma unroll
        for (int nt = 0; nt < 16; nt++) accs[mt][nt] = (f32x4){0.f,0.f,0.f,0.f};
    #pragma unroll
    for (int nt = 0; nt < 16; nt++){
        bf16x8 bk0 = *(const bf16x8*)(Ks + (nt*16 + lm)*72 +  0 + lq*8);
        bf16x8 bk1 = *(const bf16x8*)(Ks + (nt*16 + lm)*72 + 32 + lq*8);
        #pragma unroll
        for (int mt = 0; mt < 2; mt++){
            accs[mt][nt] = __builtin_amdgcn_mfma_f32_16x16x32_bf16(aq[mt][0], bk0, accs[mt][nt], 0, 0, 0);
            accs[mt][nt] = __builtin_amdgcn_mfma_f32_16x16x32_bf16(aq[mt][1], bk1, accs[mt][nt], 0, 0, 0);
        }
    }

    // ---- softmax over the in-register tile (register-only; before barrier) ----
    float mxv[2][4];
    #pragma unroll
    for (int mt = 0; mt < 2; mt++)
        #pragma unroll
        for (int r = 0; r < 4; r++){
            float m = -1e30f;
            #pragma unroll
            for (int nt = 0; nt < 16; nt++) m = fmaxf(m, accs[mt][nt][r]);
            m *= 0.125f;
            m = fmaxf(m, __shfl_xor(m, 1));
            m = fmaxf(m, __shfl_xor(m, 2));
            m = fmaxf(m, __shfl_xor(m, 4));
            m = fmaxf(m, __shfl_xor(m, 8));
            mxv[mt][r] = m;
        }
    float smv[2][4] = {{0.f,0.f,0.f,0.f},{0.f,0.f,0.f,0.f}};
    #pragma unroll
    for (int mt = 0; mt < 2; mt++)
        #pragma unroll
        for (int nt = 0; nt < 16; nt++)
            #pragma unroll
            for (int r = 0; r < 4; r++){
                float p = __expf(accs[mt][nt][r]*0.125f - mxv[mt][r]);
                smv[mt][r] += p;
                accs[mt][nt][r] = p;        // overwrite score with exp in place
            }
    float inv[2][4];
    #pragma unroll
    for (int mt = 0; mt < 2; mt++)
        #pragma unroll
        for (int r = 0; r < 4; r++){
            float s = smv[mt][r];
            s += __shfl_xor(s, 1); s += __shfl_xor(s, 2);
            s += __shfl_xor(s, 4); s += __shfl_xor(s, 8);
            inv[mt][r] = 1.f / s;
        }

    // ---- barrier: Ks reads done everywhere; now safe to overwrite region with Ps ----
    __syncthreads();
    const int woff = wave * (32*264);
    #pragma unroll
    for (int mt = 0; mt < 2; mt++)
        #pragma unroll
        for (int nt = 0; nt < 16; nt++)
            #pragma unroll
            for (int r = 0; r < 4; r++)
                Ps[woff + (mt*16 + lq*4 + r)*264 + nt*16 + lm] = f2b(accs[mt][nt][r]);
    __syncthreads();

    // ---- PV: ctx[32x64] = P[32x256] @ V[256x64]  (B-frags from transposed Vt) ----
    f32x4 accc[2][4];
    #pragma unroll
    for (int mt = 0; mt < 2; mt++)
        #pragma unroll
        for (int nt = 0; nt < 4; nt++) accc[mt][nt] = (f32x4){0.f,0.f,0.f,0.f};
    #pragma unroll
    for (int kk = 0; kk < 8; kk++){
        bf16x8 pa0 = *(const bf16x8*)(Ps + woff + ( 0 + lm)*264 + kk*32 + lq*8);
        bf16x8 pa1 = *(const bf16x8*)(Ps + woff + (16 + lm)*264 + kk*32 + lq*8);
        #pragma unroll
        for (int nt = 0; nt < 4; nt++){
            bf16x8 bv = *(const bf16x8*)(Vt + (nt*16 + lm)*264 + kk*32 + lq*8);
            accc[0][nt] = __builtin_amdgcn_mfma_f32_16x16x32_bf16(pa0, bv, accc[0][nt], 0, 0, 0);
            accc[1][nt] = __builtin_amdgcn_mfma_f32_16x16x32_bf16(pa1, bv, accc[1][nt], 0, 0, 0);
        }
    }

    // ---- normalize + store ctx ----
    #pragma unroll
    for (int mt = 0; mt < 2; mt++)
        #pragma unroll
        for (int nt = 0; nt < 4; nt++)
            #pragma unroll
            for (int r = 0; r < 4; r++){
                int srow = wave*32 + mt*16 + lq*4 + r;
                int ch = nt*16 + lm;
                float v = accc[mt][nt][r] * inv[mt][r];
                ctxb[(long)(b*SS + srow)*HH + h*HDIM + ch] = f2b(v);
            }
}

// ---------------- persistent GRU scan: 32 blocks, custom light-weight grid barrier ------------
// Block owns 16 hidden columns (j0..j0+15) of all 3 gates; Whh slice in LDS for all 128 steps.
// h exchange: bf16 double buffer in global. MFMA A-fragments read DIRECTLY from global (each
// block consumes each h byte exactly once -> LDS staging would be pure latency).
// Barrier: monotonic counter, wave-granularity arrivals (128/step), release/acquire threadfence.
__global__ __launch_bounds__(256) void k_gru_all(
    const float* __restrict__ gi, const u16* __restrict__ whh, const u16* __restrict__ bhh,
    const u16* __restrict__ h0b, u16* __restrict__ hx0, u16* __restrict__ hx1,
    u16* __restrict__ hout, int* __restrict__ bar)
{
    __shared__ u16 wlds[48*520];   // 3 gates x 16 rows, ld=520
    const int tid = threadIdx.x;
    const int j0 = blockIdx.x * 16;
    const int wave = tid >> 6, lane = tid & 63;
    const int lm = lane & 15, lq = lane >> 4;

    // ---- stage Whh slice once: rows (g*512 + j0 + 0..15), 512 wide ----
    #pragma unroll
    for (int i = 0; i < 12; i++){
        int c = i*256 + tid;               // 3072 chunks of 8
        int rl = c >> 6, kc = (c & 63) << 3;
        int g = rl >> 4, jr = rl & 15;
        *(uint4*)(wlds + rl*520 + kc) = *(const uint4*)(whh + (long)(g*512 + j0 + jr)*HH + kc);
    }
    __syncthreads();

    const int j = j0 + lm;
    const float br = b2f(bhh[j]), bz = b2f(bhh[512 + j]), bn = b2f(bhh[1024 + j]);
    const int brow = wave*16 + lm;
    float hp[4];
    #pragma unroll
    for (int r = 0; r < 4; r++) hp[r] = b2f(h0b[(wave*16 + lq*4 + r)*HH + j]);

    const u16* hsrc = h0b;
    for (int s = 0; s < SS; s++){
        // ---- A-fragments straight from global (16 independent 16B loads, one latency) ----
        bf16x8 af[16];
        #pragma unroll
        for (int k = 0; k < 16; k++)
            af[k] = *(const bf16x8*)(hsrc + (long)brow*HH + k*32 + lq*8);
        // ---- gi loads (independent of h; in flight alongside af) ----
        float gir[4], giz[4], gin[4];
        #pragma unroll
        for (int r = 0; r < 4; r++){
            int b = wave*16 + lq*4 + r;
            long gbase = (long)(b*SS + s)*1536;
            gir[r] = gi[gbase + j];
            giz[r] = gi[gbase + 512 + j];
            gin[r] = gi[gbase + 1024 + j];
        }
        f32x4 acc[3];
        acc[0] = (f32x4){0.f,0.f,0.f,0.f};
        acc[1] = acc[0]; acc[2] = acc[0];
        #pragma unroll
        for (int k = 0; k < 16; k++){
            #pragma unroll
            for (int g = 0; g < 3; g++){
                bf16x8 wf = *(const bf16x8*)(wlds + (g*16 + lm)*520 + k*32 + lq*8);
                acc[g] = __builtin_amdgcn_mfma_f32_16x16x32_bf16(af[k], wf, acc[g], 0, 0, 0);
            }
        }
        u16* hdst = (s & 1) ? hx1 : hx0;
        #pragma unroll
        for (int r = 0; r < 4; r++){
            int b = wave*16 + lq*4 + r;
            float rg = 1.f/(1.f + __expf(-(gir[r] + acc[0][r] + br)));
            float zg = 1.f/(1.f + __expf(-(giz[r] + acc[1][r] + bz)));
            float ng = tanhf(gin[r] + rg*(acc[2][r] + bn));
            float hv = (1.f - zg)*ng + zg*hp[r];
            hp[r] = hv;
            u16 hb = f2b(hv);
            hdst[b*HH + j] = hb;
            hout[(long)(b*SS + s)*HH + j] = hb;
        }
        // ---- grid barrier: wave-granularity arrivals, monotonic counter ----
        __threadfence();                                   // release: this wave's h stores visible
        if (lane == 0){
            atomicAdd(bar, 1);
            const int target = 128*(s+1);                  // 32 blocks x 4 waves
            while (__hip_atomic_load(bar, __ATOMIC_RELAXED, __HIP_MEMORY_SCOPE_AGENT) < target)
                __builtin_amdgcn_s_sleep(1);
        }
        __threadfence();                                   // acquire: invalidate before next reads
        hsrc = hdst;
    }
}

// ---------------- row softmax over V=8000: ws bf16 logits -> d_out (bf16 or f32 per flag) -------
__global__ __launch_bounds__(256) void k_softmax(const u16* __restrict__ logits, void* __restrict__ out,
                                                 const int* __restrict__ flag)
{
    __shared__ float red[4];
    __shared__ float red2[4];
    long row = blockIdx.x;
    const u16* p = logits + row*VV;
    int tid = threadIdx.x, wave = tid >> 6, lane = tid & 63;
    float v[32];
    float mx = -1e30f;
    #pragma unroll
    for (int i = 0; i < 32; i++){
        int c = tid + i*256;
        v[i] = (c < VV) ? b2f(p[c]) : -1e30f;
        mx = fmaxf(mx, v[i]);
    }
    #pragma unroll
    for (int off = 1; off < 64; off <<= 1) mx = fmaxf(mx, __shfl_xor(mx, off));
    if (lane == 0) red[wave] = mx;
    __syncthreads();
    mx = fmaxf(fmaxf(red[0], red[1]), fmaxf(red[2], red[3]));
    float sum = 0.f;
    #pragma unroll
    for (int i = 0; i < 32; i++){
        int c = tid + i*256;
        if (c < VV){ v[i] = __expf(v[i] - mx); sum += v[i]; }
    }
    #pragma unroll
    for (int off = 1; off < 64; off <<= 1) sum += __shfl_xor(sum, off);
    if (lane == 0) red2[wave] = sum;
    __syncthreads();
    float inv = 1.f / (red2[0] + red2[1] + red2[2] + red2[3]);
    int f = *flag;
    float* pf = (float*)out + row*VV;
    u16*  pb = (u16*)out + row*VV;
    #pragma unroll
    for (int i = 0; i < 32; i++){
        int c = tid + i*256;
        if (c < VV){
            float r = v[i]*inv;
            if (f) pf[c] = r; else pb[c] = f2b(r);
        }
    }
}

// ---------------- hidden copy: ws bf16 -> d_out (bf16 or f32 per flag) ----------------
__global__ __launch_bounds__(256) void k_hidout(const u16* __restrict__ hid, void* __restrict__ out,
                                                const int* __restrict__ flag)
{
    long i = (long)blockIdx.x * 256 + threadIdx.x;   // grid 16384 -> 4,194,304
    u16 h = hid[i];
    if (*flag) ((float*)out + (size_t)M1*VV)[i] = b2f(h);
    else       ((u16*)out  + (size_t)M1*VV)[i] = h;
}

extern "C" void kernel_launch(void* const* d_in, const int* in_sizes, int n_in,
                              void* d_out, int out_size, void* d_ws, size_t ws_size,
                              hipStream_t stream)
{
    const int* pc = (const int*)d_in[1];

    const size_t MB = 1u << 20;
    char* w = (char*)d_ws;
    // ---- pipeline overlay [0, 126 MiB) ----
    u16* qin   = (u16*)(w + 0);
    u16* ctxb  = (u16*)(w + 0);
    u16* Qb    = (u16*)(w + 8*MB);
    u16* Kb    = (u16*)(w + 16*MB);
    u16* Vb    = (u16*)(w + 32*MB);
    u16* gruin = (u16*)(w + 48*MB);
    float* gi  = (float*)(w + 0);          // 48 MiB, after attn phase dead
    u16* logits= (u16*)(w + 0);            // 125 MiB, after GRU phase dead
    // ---- persistent converted inputs [126 MiB, 176 MiB) ----
    u16* enc_b = (u16*)(w + 126*MB);       // 16 MiB
    u16* emb_b = (u16*)(w + 142*MB);       // 8 MiB
    u16* pw_b  = (u16*)(w + 150*MB);       // 8 MiB
    u16* wih_b = (u16*)(w + 158*MB);       // 3 MiB
    u16* whh_b = (u16*)(w + 161*MB);       // 2 MiB
    u16* ipw_b = (u16*)(w + 163*MB);       // 2 MiB
    u16* opw_b = (u16*)(w + 165*MB);       // 1 MiB
    u16* h0_b  = (u16*)(w + 166*MB);
    u16* ipb_b = (u16*)(w + 166*MB + 128*1024);
    u16* opb_b = (u16*)(w + 166*MB + 192*1024);
    u16* bih_b = (u16*)(w + 166*MB + 256*1024);
    u16* bhh_b = (u16*)(w + 166*MB + 320*1024);
    u16* pb_b  = (u16*)(w + 166*MB + 384*1024);
    int* flag  = (int*)(w + 166*MB + 448*1024);
    int* bar   = (int*)(w + 166*MB + 452*1024);      // GRU barrier counter (zeroed by k_probe)
    u16* hx0   = (u16*)(w + 167*MB);                 // 64 KB bf16 h exchange buf 0
    u16* hx1   = (u16*)(w + 167*MB + 128*1024);      // 64 KB bf16 h exchange buf 1
    u16* hid_b = (u16*)(w + 168*MB);       // 8 MiB

    // ---- dtype probe + barrier zero + input normalization to bf16 ----
    k_probe<<<1, 256, 0, stream>>>((const u16*)d_in[3], flag, bar);
    struct { const void* s; u16* d; long n; } cv[13] = {
        { d_in[0],  enc_b, (long)M2*HH },
        { d_in[2],  h0_b,  BB*HH },
        { d_in[3],  emb_b, (long)VV*HH },
        { d_in[4],  ipw_b, 3*HH*HH },
        { d_in[5],  ipb_b, 3*HH },
        { d_in[6],  opw_b, HH*HH },
        { d_in[7],  opb_b, HH },
        { d_in[8],  wih_b, 3L*HH*2*HH },
        { d_in[9],  whh_b, 3*HH*HH },
        { d_in[10], bih_b, 3*HH },
        { d_in[11], bhh_b, 3*HH },
        { d_in[12], pw_b,  (long)VV*HH },
        { d_in[13], pb_b,  VV },
    };
    for (int i = 0; i < 13; i++){
        long n8 = cv[i].n >> 3;
        k_convert<<<(int)((n8 + 255)/256), 256, 0, stream>>>(cv[i].s, cv[i].d, flag, n8);
    }

    k_embed<<<2048, 256, 0, stream>>>(pc, emb_b, h0_b, gruin, qin);
    gemm_bt<<<dim3(64,4),  256, 0, stream>>>(qin,   HH, ipw_b,            HH, ipb_b,      Qb,  nullptr, HH,  HH, HH);
    gemm_bt<<<dim3(128,4), 256, 0, stream>>>(enc_b, HH, ipw_b + 512*512,  HH, ipb_b+512,  Kb,  nullptr, HH,  HH, HH);
    gemm_bt<<<dim3(128,4), 256, 0, stream>>>(enc_b, HH, ipw_b + 1024*512, HH, ipb_b+1024, Vb,  nullptr, HH,  HH, HH);
    k_attn<<<BB*NHEAD, 256, 0, stream>>>(Qb, Kb, Vb, ctxb);   // 512 blocks, one per (b,h)
    gemm_bt<<<dim3(64,4),  256, 0, stream>>>(ctxb, HH, opw_b, HH, opb_b, gruin + 512, nullptr, 2*HH, HH, HH);
    gemm_bt<<<dim3(64,12), 256, 0, stream>>>(gruin, 2*HH, wih_b, 2*HH, bih_b, nullptr, gi, 1536, 1536, 2*HH);

    // ---- persistent cooperative GRU scan (custom barrier; cooperative launch for co-residency) --
    {
        const float* gia = gi; const u16* whha = whh_b; const u16* bhha = bhh_b;
        const u16* h0a = h0_b; u16* hx0a = hx0; u16* hx1a = hx1; u16* hida = hid_b;
        int* bara = bar;
        void* gru_args[] = { (void*)&gia, (void*)&whha, (void*)&bhha, (void*)&h0a,
                             (void*)&hx0a, (void*)&hx1a, (void*)&hida, (void*)&bara };
        hipLaunchCooperativeKernel((const void*)k_gru_all, dim3(32), dim3(256),
                                   gru_args, 0, stream);
    }

    gemm_bt<<<dim3(64,63), 256, 0, stream>>>(hid_b, HH, pw_b, HH, pb_b, logits, nullptr, VV, VV, HH);
    k_softmax<<<M1, 256, 0, stream>>>(logits, d_out, flag);
    k_hidout<<<16384, 256, 0, stream>>>(hid_b, d_out, flag);
}

// Round 6
// 1569.173 us; speedup vs baseline: 1.5012x; 1.5012x over previous
//
#include <hip/hip_runtime.h>
#include <hip/hip_bf16.h>

#define BB 64
#define SS 128
#define LSRC 256
#define HH 512
#define NHEAD 8
#define HDIM 64
#define VV 8000
#define M1 (BB*SS)     // 8192
#define M2 (BB*LSRC)   // 16384

typedef unsigned short u16;
typedef __attribute__((ext_vector_type(8))) short bf16x8;
typedef __attribute__((ext_vector_type(4))) float f32x4;

__device__ __forceinline__ float b2f(u16 u){
    unsigned int x = ((unsigned int)u) << 16;
    return __uint_as_float(x);
}
__device__ __forceinline__ u16 f2b(float f){
    unsigned int x = __float_as_uint(f);
    x = x + 0x7fffu + ((x >> 16) & 1u);
    return (u16)(x >> 16);
}

// ---------------- dtype probe: bf16 data never has exp>=0x80 (|x|>=2); f32 low-mantissa halves do ~50%
// Also zeroes the GRU barrier region (runs first on the stream): 32 slots at bar[i*32] (128B apart).
__global__ __launch_bounds__(256) void k_probe(const u16* __restrict__ emb, int* __restrict__ flag,
                                               int* __restrict__ bar){
    __shared__ int tot;
    if (threadIdx.x == 0) tot = 0;
    #pragma unroll
    for (int i = 0; i < 5; i++) bar[threadIdx.x + i*256] = 0;
    __syncthreads();
    int cnt = 0;
    #pragma unroll
    for (int i = 0; i < 32; i++){
        u16 u = emb[threadIdx.x * 32 + i];
        cnt += (((u >> 7) & 0xFF) >= 0x80);
    }
    #pragma unroll
    for (int off = 1; off < 64; off <<= 1) cnt += __shfl_xor(cnt, off);
    if ((threadIdx.x & 63) == 0) atomicAdd(&tot, cnt);
    __syncthreads();
    if (threadIdx.x == 0) *flag = (tot > 100) ? 1 : 0;
}

// ---------------- input normalization: f32->bf16 convert, or bf16 passthrough copy ----------------
__global__ __launch_bounds__(256) void k_convert(const void* __restrict__ src, u16* __restrict__ dst,
                                                 const int* __restrict__ flag, long n8){
    long i = (long)blockIdx.x * 256 + threadIdx.x;
    if (i >= n8) return;
    if (*flag){
        const float4* s = (const float4*)src;
        float4 a = s[i*2], b = s[i*2+1];
        u16 o[8] = { f2b(a.x), f2b(a.y), f2b(a.z), f2b(a.w), f2b(b.x), f2b(b.y), f2b(b.z), f2b(b.w) };
        *(uint4*)(dst + i*8) = *(const uint4*)o;
    } else {
        *(uint4*)(dst + i*8) = ((const uint4*)src)[i];
    }
}

// ---------------- embed + query_input ----------------
__global__ __launch_bounds__(256) void k_embed(const int* __restrict__ pc,
    const u16* __restrict__ emb, const u16* __restrict__ h0,
    u16* __restrict__ gruin, u16* __restrict__ qin)
{
    int c = blockIdx.x * 256 + threadIdx.x;   // 524288 chunks of 8 elems
    int row = c >> 6;
    int kc = (c & 63) << 3;
    int b = row >> 7;
    int tok = pc[row];
    uint4 e = *(const uint4*)(emb + (long)tok * HH + kc);
    *(uint4*)(gruin + (long)row * (2*HH) + kc) = e;   // char_emb -> gru_input[:, :512]
    uint4 hv = *(const uint4*)(h0 + b * HH + kc);
    const u16* ep = (const u16*)&e;
    const u16* hp = (const u16*)&hv;
    u16 q[8];
    #pragma unroll
    for (int j = 0; j < 8; j++) q[j] = f2b(b2f(ep[j]) + b2f(hp[j]));
    *(uint4*)(qin + (long)row * HH + kc) = *(const uint4*)q;
}

// ---------------- generic bf16 MFMA GEMM: C[M,N] = A[M,K] * W[N,K]^T + bias ----------------
__global__ __launch_bounds__(256) void gemm_bt(
    const u16* __restrict__ A, int lda,
    const u16* __restrict__ W, int ldw,
    const u16* __restrict__ bias,
    u16* __restrict__ Cb, float* __restrict__ Cf, int ldc,
    int N, int K)
{
    __shared__ u16 As[128*64];
    __shared__ u16 Bs[128*64];
    const int tid = threadIdx.x;
    const int wave = tid >> 6, lane = tid & 63;
    const int m0 = blockIdx.x * 128, n0 = blockIdx.y * 128;
    const int wm = (wave & 1) * 64, wn = (wave >> 1) * 64;
    const int lm = lane & 15, lq = lane >> 4;
    f32x4 acc[4][4];
    #pragma unroll
    for (int i = 0; i < 4; i++)
        #pragma unroll
        for (int j = 0; j < 4; j++) acc[i][j] = (f32x4){0.f,0.f,0.f,0.f};

    for (int k0 = 0; k0 < K; k0 += 64) {
        #pragma unroll
        for (int i = 0; i < 4; i++) {
            int chunk = i*256 + tid;               // 1024 chunks of 8 bf16
            int row = chunk >> 3, kc = (chunk & 7) << 3;
            *(uint4*)(As + chunk*8) = *(const uint4*)(A + (long)(m0+row)*lda + k0 + kc);
            int brow = n0 + row; if (brow >= N) brow = N - 1;   // clamp for N=8000 tail
            *(uint4*)(Bs + chunk*8) = *(const uint4*)(W + (long)brow*ldw + k0 + kc);
        }
        __syncthreads();
        #pragma unroll
        for (int kk = 0; kk < 64; kk += 32) {
            bf16x8 af[4], bfr[4];
            #pragma unroll
            for (int i = 0; i < 4; i++){
                af[i]  = *(const bf16x8*)(As + (wm + i*16 + lm)*64 + kk + lq*8);
                bfr[i] = *(const bf16x8*)(Bs + (wn + i*16 + lm)*64 + kk + lq*8);
            }
            #pragma unroll
            for (int mi = 0; mi < 4; mi++)
                #pragma unroll
                for (int ni = 0; ni < 4; ni++)
                    acc[mi][ni] = __builtin_amdgcn_mfma_f32_16x16x32_bf16(af[mi], bfr[ni], acc[mi][ni], 0, 0, 0);
        }
        __syncthreads();
    }
    // C/D layout: col = lane&15, row = (lane>>4)*4 + reg
    #pragma unroll
    for (int ni = 0; ni < 4; ni++){
        int n = n0 + wn + ni*16 + lm;
        if (n >= N) continue;
        float bv = bias ? b2f(bias[n]) : 0.f;
        #pragma unroll
        for (int mi = 0; mi < 4; mi++){
            #pragma unroll
            for (int r = 0; r < 4; r++){
                int m = m0 + wm + mi*16 + lq*4 + r;
                float v = acc[mi][ni][r] + bv;
                if (Cf) Cf[(long)m*ldc + n] = v;
                else    Cb[(long)m*ldc + n] = f2b(v);
            }
        }
    }
}

// ---------------- fused MFMA attention: one block per (b, head) ----------------
// scores = Q[128x64] @ K[256x64]^T * 0.125 -> row softmax -> ctx = P @ V[256x64]
// LDS overlay: Ps reuses the Ks region (Ks dead after QK^T) -> 99 KiB static LDS total.
__global__ __launch_bounds__(256) void k_attn(const u16* __restrict__ Qb,
    const u16* __restrict__ Kb, const u16* __restrict__ Vb, u16* __restrict__ ctxb)
{
    __shared__ u16 smem[64*264 + 4*32*264];   // Vt [16896] + union(Ks[18432], Ps[33792]) = 101,376 B
    u16* Vt = smem;                // V transposed [ch][l], ld=264
    u16* Ks = smem + 64*264;       // K row-major, ld=72 (alive during QK^T only)
    u16* Ps = smem + 64*264;       // per-wave P [32][l], ld=264 (alive during PV only)
    const int bid = blockIdx.x;
    const int h = bid & 7, b = bid >> 3;
    const int tid = threadIdx.x;
    const int wave = tid >> 6, lane = tid & 63;
    const int lm = lane & 15, lq = lane >> 4;
    const long kvbase = (long)b*LSRC*HH + h*HDIM;

    // ---- stage K (row-major) and V (transposed) into LDS ----
    #pragma unroll
    for (int i = 0; i < 8; i++){
        int c = i*256 + tid;                // 2048 chunks: l = c>>3, ch0 = (c&7)*8
        int l = c >> 3, ch0 = (c & 7) << 3;
        uint4 kv = *(const uint4*)(Kb + kvbase + (long)l*HH + ch0);
        *(uint4*)(Ks + l*72 + ch0) = kv;
        uint4 vv = *(const uint4*)(Vb + kvbase + (long)l*HH + ch0);
        const u16* vp = (const u16*)&vv;
        #pragma unroll
        for (int j = 0; j < 8; j++) Vt[(ch0 + j)*264 + l] = vp[j];
    }

    // ---- Q fragments straight from global (wave's 32 rows) ----
    bf16x8 aq[2][2];
    #pragma unroll
    for (int mt = 0; mt < 2; mt++)
        #pragma unroll
        for (int kk = 0; kk < 2; kk++)
            aq[mt][kk] = *(const bf16x8*)(Qb + (long)(b*SS + wave*32 + mt*16 + lm)*HH
                                              + h*HDIM + kk*32 + lq*8);
    __syncthreads();

    // ---- QK^T: 32x256 score tile in registers ----
    f32x4 accs[2][16];
    #pragma unroll
    for (int mt = 0; mt < 2; mt++)
        #pragma unroll
        for (int nt = 0; nt < 16; nt++) accs[mt][nt] = (f32x4){0.f,0.f,0.f,0.f};
    #pragma unroll
    for (int nt = 0; nt < 16; nt++){
        bf16x8 bk0 = *(const bf16x8*)(Ks + (nt*16 + lm)*72 +  0 + lq*8);
        bf16x8 bk1 = *(const bf16x8*)(Ks + (nt*16 + lm)*72 + 32 + lq*8);
        #pragma unroll
        for (int mt = 0; mt < 2; mt++){
            accs[mt][nt] = __builtin_amdgcn_mfma_f32_16x16x32_bf16(aq[mt][0], bk0, accs[mt][nt], 0, 0, 0);
            accs[mt][nt] = __builtin_amdgcn_mfma_f32_16x16x32_bf16(aq[mt][1], bk1, accs[mt][nt], 0, 0, 0);
        }
    }

    // ---- softmax over the in-register tile (register-only; before barrier) ----
    float mxv[2][4];
    #pragma unroll
    for (int mt = 0; mt < 2; mt++)
        #pragma unroll
        for (int r = 0; r < 4; r++){
            float m = -1e30f;
            #pragma unroll
            for (int nt = 0; nt < 16; nt++) m = fmaxf(m, accs[mt][nt][r]);
            m *= 0.125f;
            m = fmaxf(m, __shfl_xor(m, 1));
            m = fmaxf(m, __shfl_xor(m, 2));
            m = fmaxf(m, __shfl_xor(m, 4));
            m = fmaxf(m, __shfl_xor(m, 8));
            mxv[mt][r] = m;
        }
    float smv[2][4] = {{0.f,0.f,0.f,0.f},{0.f,0.f,0.f,0.f}};
    #pragma unroll
    for (int mt = 0; mt < 2; mt++)
        #pragma unroll
        for (int nt = 0; nt < 16; nt++)
            #pragma unroll
            for (int r = 0; r < 4; r++){
                float p = __expf(accs[mt][nt][r]*0.125f - mxv[mt][r]);
                smv[mt][r] += p;
                accs[mt][nt][r] = p;        // overwrite score with exp in place
            }
    float inv[2][4];
    #pragma unroll
    for (int mt = 0; mt < 2; mt++)
        #pragma unroll
        for (int r = 0; r < 4; r++){
            float s = smv[mt][r];
            s += __shfl_xor(s, 1); s += __shfl_xor(s, 2);
            s += __shfl_xor(s, 4); s += __shfl_xor(s, 8);
            inv[mt][r] = 1.f / s;
        }

    // ---- barrier: Ks reads done everywhere; now safe to overwrite region with Ps ----
    __syncthreads();
    const int woff = wave * (32*264);
    #pragma unroll
    for (int mt = 0; mt < 2; mt++)
        #pragma unroll
        for (int nt = 0; nt < 16; nt++)
            #pragma unroll
            for (int r = 0; r < 4; r++)
                Ps[woff + (mt*16 + lq*4 + r)*264 + nt*16 + lm] = f2b(accs[mt][nt][r]);
    __syncthreads();

    // ---- PV: ctx[32x64] = P[32x256] @ V[256x64]  (B-frags from transposed Vt) ----
    f32x4 accc[2][4];
    #pragma unroll
    for (int mt = 0; mt < 2; mt++)
        #pragma unroll
        for (int nt = 0; nt < 4; nt++) accc[mt][nt] = (f32x4){0.f,0.f,0.f,0.f};
    #pragma unroll
    for (int kk = 0; kk < 8; kk++){
        bf16x8 pa0 = *(const bf16x8*)(Ps + woff + ( 0 + lm)*264 + kk*32 + lq*8);
        bf16x8 pa1 = *(const bf16x8*)(Ps + woff + (16 + lm)*264 + kk*32 + lq*8);
        #pragma unroll
        for (int nt = 0; nt < 4; nt++){
            bf16x8 bv = *(const bf16x8*)(Vt + (nt*16 + lm)*264 + kk*32 + lq*8);
            accc[0][nt] = __builtin_amdgcn_mfma_f32_16x16x32_bf16(pa0, bv, accc[0][nt], 0, 0, 0);
            accc[1][nt] = __builtin_amdgcn_mfma_f32_16x16x32_bf16(pa1, bv, accc[1][nt], 0, 0, 0);
        }
    }

    // ---- normalize + store ctx ----
    #pragma unroll
    for (int mt = 0; mt < 2; mt++)
        #pragma unroll
        for (int nt = 0; nt < 4; nt++)
            #pragma unroll
            for (int r = 0; r < 4; r++){
                int srow = wave*32 + mt*16 + lq*4 + r;
                int ch = nt*16 + lm;
                float v = accc[mt][nt][r] * inv[mt][r];
                ctxb[(long)(b*SS + srow)*HH + h*HDIM + ch] = f2b(v);
            }
}

// ---------------- persistent GRU scan: 32 blocks, symmetric one-level all-gather barrier ------
// Block owns 16 hidden columns of all 3 gates; Whh slice in LDS for all 128 steps.
// h exchange: bf16 double buffer in global; A-fragments read directly from global with the
// whole load batch pinned before the MFMA loop (one latency, not 16 serial round-trips).
// Barrier per step: (1) __syncthreads (drains stores), (2) tid0: release fence + monotonic
// store s+1 to OWN 128B-spaced slot (single writer, no RMW), (3) wave0 lanes 0..31: poll all
// 32 slots until >= s+1 (each block waits on all arrivals directly - no publisher hop, fully
// symmetric, deadlock-free: every block stores before waiting), (4) __syncthreads + acquire
// fence. Fence structure identical to round 4 (correctness-proven on HW).
__global__ __launch_bounds__(256) void k_gru_all(
    const float* __restrict__ gi, const u16* __restrict__ whh, const u16* __restrict__ bhh,
    const u16* __restrict__ h0b, u16* __restrict__ hx0, u16* __restrict__ hx1,
    u16* __restrict__ hout, int* __restrict__ bar)
{
    __shared__ u16 wlds[48*520];   // 3 gates x 16 rows, ld=520
    const int tid = threadIdx.x;
    const int bid = blockIdx.x;
    const int j0 = bid * 16;
    const int wave = tid >> 6, lane = tid & 63;
    const int lm = lane & 15, lq = lane >> 4;

    // ---- stage Whh slice once: rows (g*512 + j0 + 0..15), 512 wide ----
    #pragma unroll
    for (int i = 0; i < 12; i++){
        int c = i*256 + tid;               // 3072 chunks of 8
        int rl = c >> 6, kc = (c & 63) << 3;
        int g = rl >> 4, jr = rl & 15;
        *(uint4*)(wlds + rl*520 + kc) = *(const uint4*)(whh + (long)(g*512 + j0 + jr)*HH + kc);
    }
    __syncthreads();

    const int j = j0 + lm;
    const float br = b2f(bhh[j]), bz = b2f(bhh[512 + j]), bn = b2f(bhh[1024 + j]);
    const int brow = wave*16 + lm;
    float hp[4];
    #pragma unroll
    for (int r = 0; r < 4; r++) hp[r] = b2f(h0b[(wave*16 + lq*4 + r)*HH + j]);

    const u16* hsrc = h0b;
    for (int s = 0; s < SS; s++){
        // ---- A-fragments + gi: issue ALL loads, then pin with sched_barrier so the
        //      MFMA loop can't sink loads into itself (one latency for the whole batch) ----
        bf16x8 af[16];
        #pragma unroll
        for (int k = 0; k < 16; k++)
            af[k] = *(const bf16x8*)(hsrc + (long)brow*HH + k*32 + lq*8);
        float gir[4], giz[4], gin[4];
        #pragma unroll
        for (int r = 0; r < 4; r++){
            int b = wave*16 + lq*4 + r;
            long gbase = (long)(b*SS + s)*1536;
            gir[r] = gi[gbase + j];
            giz[r] = gi[gbase + 512 + j];
            gin[r] = gi[gbase + 1024 + j];
        }
        __builtin_amdgcn_sched_barrier(0);
        f32x4 acc[3];
        acc[0] = (f32x4){0.f,0.f,0.f,0.f};
        acc[1] = acc[0]; acc[2] = acc[0];
        #pragma unroll
        for (int k = 0; k < 16; k++){
            #pragma unroll
            for (int g = 0; g < 3; g++){
                bf16x8 wf = *(const bf16x8*)(wlds + (g*16 + lm)*520 + k*32 + lq*8);
                acc[g] = __builtin_amdgcn_mfma_f32_16x16x32_bf16(af[k], wf, acc[g], 0, 0, 0);
            }
        }
        u16* hdst = (s & 1) ? hx1 : hx0;
        #pragma unroll
        for (int r = 0; r < 4; r++){
            int b = wave*16 + lq*4 + r;
            float rg = 1.f/(1.f + __expf(-(gir[r] + acc[0][r] + br)));
            float zg = 1.f/(1.f + __expf(-(giz[r] + acc[1][r] + bz)));
            float ng = tanhf(gin[r] + rg*(acc[2][r] + bn));
            float hv = (1.f - zg)*ng + zg*hp[r];
            hp[r] = hv;
            u16 hb = f2b(hv);
            hdst[b*HH + j] = hb;
            hout[(long)(b*SS + s)*HH + j] = hb;
        }
        // ---- symmetric all-gather barrier ----
        __syncthreads();                       // all waves' h stores vmcnt-drained at barrier
        if (tid == 0){
            __threadfence();                   // release: writeback before arrival visible
            __hip_atomic_store(&bar[bid*32], s+1, __ATOMIC_RELAXED, __HIP_MEMORY_SCOPE_AGENT);
        }
        if (tid < 32){
            while (__hip_atomic_load(&bar[tid*32], __ATOMIC_RELAXED, __HIP_MEMORY_SCOPE_AGENT) <= s)
                __builtin_amdgcn_s_sleep(1);
        }
        __syncthreads();                       // block released once wave 0 sees all arrivals
        __threadfence();                       // acquire: invalidate before next h reads
        hsrc = hdst;
    }
}

// ---------------- row softmax over V=8000: ws bf16 logits -> d_out (bf16 or f32 per flag) -------
__global__ __launch_bounds__(256) void k_softmax(const u16* __restrict__ logits, void* __restrict__ out,
                                                 const int* __restrict__ flag)
{
    __shared__ float red[4];
    __shared__ float red2[4];
    long row = blockIdx.x;
    const u16* p = logits + row*VV;
    int tid = threadIdx.x, wave = tid >> 6, lane = tid & 63;
    float v[32];
    float mx = -1e30f;
    #pragma unroll
    for (int i = 0; i < 32; i++){
        int c = tid + i*256;
        v[i] = (c < VV) ? b2f(p[c]) : -1e30f;
        mx = fmaxf(mx, v[i]);
    }
    #pragma unroll
    for (int off = 1; off < 64; off <<= 1) mx = fmaxf(mx, __shfl_xor(mx, off));
    if (lane == 0) red[wave] = mx;
    __syncthreads();
    mx = fmaxf(fmaxf(red[0], red[1]), fmaxf(red[2], red[3]));
    float sum = 0.f;
    #pragma unroll
    for (int i = 0; i < 32; i++){
        int c = tid + i*256;
        if (c < VV){ v[i] = __expf(v[i] - mx); sum += v[i]; }
    }
    #pragma unroll
    for (int off = 1; off < 64; off <<= 1) sum += __shfl_xor(sum, off);
    if (lane == 0) red2[wave] = sum;
    __syncthreads();
    float inv = 1.f / (red2[0] + red2[1] + red2[2] + red2[3]);
    int f = *flag;
    float* pf = (float*)out + row*VV;
    u16*  pb = (u16*)out + row*VV;
    #pragma unroll
    for (int i = 0; i < 32; i++){
        int c = tid + i*256;
        if (c < VV){
            float r = v[i]*inv;
            if (f) pf[c] = r; else pb[c] = f2b(r);
        }
    }
}

// ---------------- hidden copy: ws bf16 -> d_out (bf16 or f32 per flag) ----------------
__global__ __launch_bounds__(256) void k_hidout(const u16* __restrict__ hid, void* __restrict__ out,
                                                const int* __restrict__ flag)
{
    long i = (long)blockIdx.x * 256 + threadIdx.x;   // grid 16384 -> 4,194,304
    u16 h = hid[i];
    if (*flag) ((float*)out + (size_t)M1*VV)[i] = b2f(h);
    else       ((u16*)out  + (size_t)M1*VV)[i] = h;
}

extern "C" void kernel_launch(void* const* d_in, const int* in_sizes, int n_in,
                              void* d_out, int out_size, void* d_ws, size_t ws_size,
                              hipStream_t stream)
{
    const int* pc = (const int*)d_in[1];

    const size_t MB = 1u << 20;
    char* w = (char*)d_ws;
    // ---- pipeline overlay [0, 126 MiB) ----
    u16* qin   = (u16*)(w + 0);
    u16* ctxb  = (u16*)(w + 0);
    u16* Qb    = (u16*)(w + 8*MB);
    u16* Kb    = (u16*)(w + 16*MB);
    u16* Vb    = (u16*)(w + 32*MB);
    u16* gruin = (u16*)(w + 48*MB);
    float* gi  = (float*)(w + 0);          // 48 MiB, after attn phase dead
    u16* logits= (u16*)(w + 0);            // 125 MiB, after GRU phase dead
    // ---- persistent converted inputs [126 MiB, 176 MiB) ----
    u16* enc_b = (u16*)(w + 126*MB);       // 16 MiB
    u16* emb_b = (u16*)(w + 142*MB);       // 8 MiB
    u16* pw_b  = (u16*)(w + 150*MB);       // 8 MiB
    u16* wih_b = (u16*)(w + 158*MB);       // 3 MiB
    u16* whh_b = (u16*)(w + 161*MB);       // 2 MiB
    u16* ipw_b = (u16*)(w + 163*MB);       // 2 MiB
    u16* opw_b = (u16*)(w + 165*MB);       // 1 MiB
    u16* h0_b  = (u16*)(w + 166*MB);
    u16* ipb_b = (u16*)(w + 166*MB + 128*1024);
    u16* opb_b = (u16*)(w + 166*MB + 192*1024);
    u16* bih_b = (u16*)(w + 166*MB + 256*1024);
    u16* bhh_b = (u16*)(w + 166*MB + 320*1024);
    u16* pb_b  = (u16*)(w + 166*MB + 384*1024);
    int* flag  = (int*)(w + 166*MB + 448*1024);
    int* bar   = (int*)(w + 166*MB + 452*1024);      // 32 arrival slots, 128B apart (zeroed by k_probe)
    u16* hx0   = (u16*)(w + 167*MB);                 // 64 KB bf16 h exchange buf 0
    u16* hx1   = (u16*)(w + 167*MB + 128*1024);      // 64 KB bf16 h exchange buf 1
    u16* hid_b = (u16*)(w + 168*MB);       // 8 MiB

    // ---- dtype probe + barrier zero + input normalization to bf16 ----
    k_probe<<<1, 256, 0, stream>>>((const u16*)d_in[3], flag, bar);
    struct { const void* s; u16* d; long n; } cv[13] = {
        { d_in[0],  enc_b, (long)M2*HH },
        { d_in[2],  h0_b,  BB*HH },
        { d_in[3],  emb_b, (long)VV*HH },
        { d_in[4],  ipw_b, 3*HH*HH },
        { d_in[5],  ipb_b, 3*HH },
        { d_in[6],  opw_b, HH*HH },
        { d_in[7],  opb_b, HH },
        { d_in[8],  wih_b, 3L*HH*2*HH },
        { d_in[9],  whh_b, 3*HH*HH },
        { d_in[10], bih_b, 3*HH },
        { d_in[11], bhh_b, 3*HH },
        { d_in[12], pw_b,  (long)VV*HH },
        { d_in[13], pb_b,  VV },
    };
    for (int i = 0; i < 13; i++){
        long n8 = cv[i].n >> 3;
        k_convert<<<(int)((n8 + 255)/256), 256, 0, stream>>>(cv[i].s, cv[i].d, flag, n8);
    }

    k_embed<<<2048, 256, 0, stream>>>(pc, emb_b, h0_b, gruin, qin);
    gemm_bt<<<dim3(64,4),  256, 0, stream>>>(qin,   HH, ipw_b,            HH, ipb_b,      Qb,  nullptr, HH,  HH, HH);
    gemm_bt<<<dim3(128,4), 256, 0, stream>>>(enc_b, HH, ipw_b + 512*512,  HH, ipb_b+512,  Kb,  nullptr, HH,  HH, HH);
    gemm_bt<<<dim3(128,4), 256, 0, stream>>>(enc_b, HH, ipw_b + 1024*512, HH, ipb_b+1024, Vb,  nullptr, HH,  HH, HH);
    k_attn<<<BB*NHEAD, 256, 0, stream>>>(Qb, Kb, Vb, ctxb);   // 512 blocks, one per (b,h)
    gemm_bt<<<dim3(64,4),  256, 0, stream>>>(ctxb, HH, opw_b, HH, opb_b, gruin + 512, nullptr, 2*HH, HH, HH);
    gemm_bt<<<dim3(64,12), 256, 0, stream>>>(gruin, 2*HH, wih_b, 2*HH, bih_b, nullptr, gi, 1536, 1536, 2*HH);

    // ---- persistent cooperative GRU scan (custom barrier; cooperative launch for co-residency) --
    {
        const float* gia = gi; const u16* whha = whh_b; const u16* bhha = bhh_b;
        const u16* h0a = h0_b; u16* hx0a = hx0; u16* hx1a = hx1; u16* hida = hid_b;
        int* bara = bar;
        void* gru_args[] = { (void*)&gia, (void*)&whha, (void*)&bhha, (void*)&h0a,
                             (void*)&hx0a, (void*)&hx1a, (void*)&hida, (void*)&bara };
        hipLaunchCooperativeKernel((const void*)k_gru_all, dim3(32), dim3(256),
                                   gru_args, 0, stream);
    }

    gemm_bt<<<dim3(64,63), 256, 0, stream>>>(hid_b, HH, pw_b, HH, pb_b, logits, nullptr, VV, VV, HH);
    k_softmax<<<M1, 256, 0, stream>>>(logits, d_out, flag);
    k_hidout<<<16384, 256, 0, stream>>>(hid_b, d_out, flag);
}